// Round 12
// baseline (45.399 us; speedup 1.0000x reference)
//
#include <hip/hip_runtime.h>
#include <math.h>

// Sizes fixed by the reference.
#define BSZ  16
#define DIM  1024
#define DPB  16        // d-channels per tile (64B global granule)
#define THREADS 1024   // waves 0-7 compute, waves 8-15 memory
#define TPB  4         // tiles per block (b = 4*bq + k), grid = 256 = 1 block/CU
#define SSTRIDE 17     // LDS float-stride per s-cell: 17*31=527==15 (mod 32)
#define BUFF 17472     // floats per buffer (covers prefetch overrun)
#define LDSB (2 * BUFF * 4)   // 139776 B -> 1 block/CU

__device__ __forceinline__ float sigmoidf_(float v) {
    return __builtin_amdgcn_rcpf(1.0f + __expf(-v));
}

extern __shared__ float xs[];

// 2D SSM run as the recurrence directly on x (== causal conv with the impulse
// response == reference FFT path, by linearity/shift-invariance/causality):
//   v[i,j] = a2*h[i-1,j] + a1*v[i-1,j] + b2*x[i,j]
//   h[i,j] = a1*h[i,j-1] + a2*v[i,j-1] + b1*x[i,j]
//   y[i,j] = <h,C1*s> + <v,C2*s>;  out = silu(y + x*omega)
//
// Anti-diagonal wavefront compute (lane = row i, step ts, j = ts-i); neighbor
// state folded into v_fmac_f32_dpp wave_shr:1 (lane0 zeroed by bound_ctrl:0,
// half-wave row-0 zeroed via a1z/a2z coefficients).
//
// R12 = R11 with the tile loop kept ROLLED (#pragma unroll 1, as in R7).
// R11's full unroll replicated the 63-step body 4x (~50KB) past the 32KB
// L1I -> instruction-fetch stalls on every wave (all pipes ~35-40% idle).
// Memory waves keep the single ROLLING prefetch register set:
//   iter k:  DRAIN(k-1 from bufO) -> STAGE(L -> bufO)  [L issued in iter
//   k-1 => complete, no vmcnt stall] -> ISSUE(L <- tile k+2).
// One 32-VGPR load set alive across barriers -> no scratch spill.
__global__ __launch_bounds__(THREADS, 1) void ssm2d_kernel(
    const float* __restrict__ x,
    const float* __restrict__ A1, const float* __restrict__ A2,
    const float* __restrict__ B1, const float* __restrict__ B2,
    const float* __restrict__ C1, const float* __restrict__ C2,
    const float* __restrict__ omega,
    float* __restrict__ out)
{
    const int bx = blockIdx.x;     // 0..255
    const int bq = bx >> 6;        // 0..3  -> tiles b = 4*bq + k
    const int d0 = (bx & 63) * DPB;
    const int t  = threadIdx.x;

    const int lane = t & 63;
    const int wv   = t >> 6;               // wave 0..15
    const int i    = lane & 31;            // compute: row owned by this lane

    // ---- compute-wave coefficients (waves 0-7 only) ----
    float a1c0, a1c1, a2c0, a2c1, b1c0, b1c1, b2c0, b2c1;
    float c1s0, c1s1, c2s0, c2s1, om;
    float a1z0, a1z1, a2z0, a2z1;
    int dd = 0;
    if (t < 512) {
        dd = 2 * wv + (lane >> 5);         // image (d-index) 0..15
        const int d = d0 + dd;
        const float2 fA1 = *reinterpret_cast<const float2*>(A1 + 2 * d);
        const float2 fA2 = *reinterpret_cast<const float2*>(A2 + 2 * d);
        const float2 fB1 = *reinterpret_cast<const float2*>(B1 + 2 * d);
        const float2 fB2 = *reinterpret_cast<const float2*>(B2 + 2 * d);
        const float2 fC1 = *reinterpret_cast<const float2*>(C1 + 2 * d);
        const float2 fC2 = *reinterpret_cast<const float2*>(C2 + 2 * d);
        om   = omega[d];
        a1c0 = sigmoidf_(fA1.x) * 0.5f;  a1c1 = sigmoidf_(fA1.y) * 0.5f;
        a2c0 = sigmoidf_(fA2.x) * 0.5f;  a2c1 = sigmoidf_(fA2.y) * 0.5f;
        b1c0 = sigmoidf_(fB1.x) * 0.5f;  b1c1 = sigmoidf_(fB1.y) * 0.5f;
        b2c0 = sigmoidf_(fB2.x) * 0.5f;  b2c1 = sigmoidf_(fB2.y) * 0.5f;
        const float sc = 0.70710678118654752f;
        c1s0 = fC1.x * sc;  c1s1 = fC1.y * sc;
        c2s0 = fC2.x * sc;  c2s1 = fC2.y * sc;
        a1z0 = (i == 0) ? 0.f : a1c0;  a1z1 = (i == 0) ? 0.f : a1c1;
        a2z0 = (i == 0) ? 0.f : a2c0;  a2z1 = (i == 0) ? 0.f : a2c1;
    }

    // ---- memory-wave mappings & the single rolling load set ----
    const int m    = t & 511;
    const int srow = m >> 2;               // 0..127
    const int qq   = (m & 3) * 4;
    const size_t gb = (size_t)srow * (BSZ * DIM) + d0 + qq;
    float4 L[8];

#define ISSUE(TILE) do {                                                     \
        const float* gp = x + gb + (size_t)(TILE) * DIM;                     \
        _Pragma("unroll") for (int k2 = 0; k2 < 8; ++k2)                     \
            L[k2] = *reinterpret_cast<const float4*>(                        \
                gp + (size_t)k2 * (128 * BSZ * DIM));                        \
    } while (0)

#define STAGEFROM(BUFO) do {                                                 \
        _Pragma("unroll") for (int k2 = 0; k2 < 8; ++k2) {                   \
            float* p = (BUFO) + SSTRIDE * (srow + 128 * k2) + qq;            \
            p[0] = L[k2].x; p[1] = L[k2].y;                                  \
            p[2] = L[k2].z; p[3] = L[k2].w; }                                \
    } while (0)

#define DRAINTO(TILE, BUFO) do {                                             \
        float* op = out + gb + (size_t)(TILE) * DIM;                         \
        _Pragma("unroll") for (int k2 = 0; k2 < 8; ++k2) {                   \
            const float* p = (BUFO) + SSTRIDE * (srow + 128 * k2) + qq;      \
            float4 v; v.x = p[0]; v.y = p[1]; v.z = p[2]; v.w = p[3];        \
            *reinterpret_cast<float4*>(                                      \
                op + (size_t)k2 * (128 * BSZ * DIM)) = v; }                  \
    } while (0)

    // ---- prologue: all threads stage tile 0; memory waves also issue L(t1) ----
    {
        const int srow4 = t >> 2;          // 0..255
        const int qq4   = (t & 3) * 4;
        const float* gp0 = x + (size_t)srow4 * (BSZ * DIM)
                             + (size_t)(4 * bq) * DIM + d0 + qq4;
        float4 P[4];
        #pragma unroll
        for (int k2 = 0; k2 < 4; ++k2)
            P[k2] = *reinterpret_cast<const float4*>(
                gp0 + (size_t)k2 * (256 * BSZ * DIM));
        if (t >= 512) ISSUE(4 * bq + 1);   // stays in flight past the barrier
        #pragma unroll
        for (int k2 = 0; k2 < 4; ++k2) {
            float* p = xs + SSTRIDE * (srow4 + 256 * k2) + qq4;
            p[0] = P[k2].x; p[1] = P[k2].y; p[2] = P[k2].z; p[3] = P[k2].w;
        }
    }
    __syncthreads();

    // ---- compute step macros ----
#define SBODY(XV_EXPR)                                                       \
        const float xv = (XV_EXPR);                                          \
        const float t10 = b1c0 * xv, t11 = b1c1 * xv;                        \
        const float hn0 = fmaf(a1c0, h0, fmaf(a2c0, v0, t10));               \
        const float hn1 = fmaf(a1c1, h1, fmaf(a2c1, v1, t11));               \
        float vn0 = b2c0 * xv, vn1 = b2c1 * xv;                              \
        asm("s_nop 1\n\t"                                                    \
            "v_fmac_f32_dpp %0, %2, %6 wave_shr:1 row_mask:0xf bank_mask:0xf bound_ctrl:0\n\t" \
            "v_fmac_f32_dpp %1, %3, %7 wave_shr:1 row_mask:0xf bank_mask:0xf bound_ctrl:0\n\t" \
            "v_fmac_f32_dpp %0, %4, %8 wave_shr:1 row_mask:0xf bank_mask:0xf bound_ctrl:0\n\t" \
            "v_fmac_f32_dpp %1, %5, %9 wave_shr:1 row_mask:0xf bank_mask:0xf bound_ctrl:0"     \
            : "+v"(vn0), "+v"(vn1)                                           \
            : "v"(h0), "v"(h1), "v"(v0), "v"(v1),                            \
              "v"(a2z0), "v"(a2z1), "v"(a1z0), "v"(a1z1));                   \
        float y = hn0 * c1s0;                                                \
        y = fmaf(hn1, c1s1, y);                                              \
        y = fmaf(vn0, c2s0, y);                                              \
        y = fmaf(vn1, c2s1, y);                                              \
        const float z = fmaf(xv, om, y);                                     \
        const float o = z * sigmoidf_(z);

#define SSTEP_PRE(TS, XQ) do {                                               \
        const bool val = (i <= (TS));                                        \
        SBODY(val ? (XQ) : 0.f)                                              \
        if (val) rp[SSTRIDE * (TS)] = o;                                     \
        h0 = hn0; h1 = hn1; v0 = vn0; v1 = vn1; } while (0)

#define SSTEP_POST(TS, XQ) do { SBODY(XQ)                                    \
        if (i >= (TS) - 31) rp[SSTRIDE * (TS)] = o;                          \
        h0 = hn0; h1 = hn1; v0 = vn0; v1 = vn1; } while (0)

    // ---- main loop: one barrier per tile; body exists ONCE (L1I-resident) ----
    #pragma unroll 1
    for (int k = 0; k < TPB; ++k) {
        if (t < 512) {
            // -------- compute waves --------
            float* rp = xs + (k & 1) * BUFF + 527 * i + dd;
            float h0 = 0.f, h1 = 0.f, v0 = 0.f, v1 = 0.f;
            float xq0 = rp[0 * SSTRIDE];
            float xq1 = rp[1 * SSTRIDE];
            float xq2 = rp[2 * SSTRIDE];
            #pragma unroll
            for (int ts = 0; ts < 30; ts += 3) {
                SSTEP_PRE(ts + 0, xq0); xq0 = rp[SSTRIDE * (ts + 3)];
                SSTEP_PRE(ts + 1, xq1); xq1 = rp[SSTRIDE * (ts + 4)];
                SSTEP_PRE(ts + 2, xq2); xq2 = rp[SSTRIDE * (ts + 5)];
            }
            SSTEP_PRE(30, xq0); xq0 = rp[SSTRIDE * 33];
            #pragma unroll
            for (int ts = 31; ts < 61; ts += 3) {
                SSTEP_POST(ts + 0, xq1); xq1 = rp[SSTRIDE * (ts + 3)];
                SSTEP_POST(ts + 1, xq2); xq2 = rp[SSTRIDE * (ts + 4)];
                SSTEP_POST(ts + 2, xq0); xq0 = rp[SSTRIDE * (ts + 5)];
            }
            SSTEP_POST(61, xq1);
            SSTEP_POST(62, xq2);
        } else {
            // -------- memory waves (rolling single load set) --------
            float* bufO = xs + ((k + 1) & 1) * BUFF;
            if (k >= 1) DRAINTO(4 * bq + k - 1, bufO);  // read bufO first
            if (k <= 2) STAGEFROM(bufO);                // L from iter k-1: ready
            if (k <= 1) ISSUE(4 * bq + k + 2);          // refill L for iter k+1
        }
        __syncthreads();
    }

    // ---- epilogue: all 1024 threads drain tile 3 from buf1 ----
    {
        const int srow4 = t >> 2;
        const int qq4   = (t & 3) * 4;
        const float* bufE = xs + ((TPB - 1) & 1) * BUFF;
        float* op = out + (size_t)srow4 * (BSZ * DIM)
                        + (size_t)(4 * bq + TPB - 1) * DIM + d0 + qq4;
        #pragma unroll
        for (int k2 = 0; k2 < 4; ++k2) {
            const float* p = bufE + SSTRIDE * (srow4 + 256 * k2) + qq4;
            float4 v; v.x = p[0]; v.y = p[1]; v.z = p[2]; v.w = p[3];
            *reinterpret_cast<float4*>(op + (size_t)k2 * (256 * BSZ * DIM)) = v;
        }
    }
}

extern "C" void kernel_launch(void* const* d_in, const int* in_sizes, int n_in,
                              void* d_out, int out_size, void* d_ws, size_t ws_size,
                              hipStream_t stream) {
    const float* x     = (const float*)d_in[0];
    const float* A1    = (const float*)d_in[1];
    const float* A2    = (const float*)d_in[2];
    const float* B1    = (const float*)d_in[3];
    const float* B2    = (const float*)d_in[4];
    const float* C1    = (const float*)d_in[5];
    const float* C2    = (const float*)d_in[6];
    const float* omega = (const float*)d_in[7];
    float* out = (float*)d_out;

    (void)hipFuncSetAttribute(reinterpret_cast<const void*>(ssm2d_kernel),
                              hipFuncAttributeMaxDynamicSharedMemorySize, LDSB);

    dim3 grid(256);                 // 64 d-groups x 4 b-quads; 4 tiles/block
    dim3 block(THREADS);
    hipLaunchKernelGGL(ssm2d_kernel, grid, block, LDSB, stream,
                       x, A1, A2, B1, B2, C1, C2, omega, out);
}

// Round 13
// 44.778 us; speedup vs baseline: 1.0139x; 1.0139x over previous
//
#include <hip/hip_runtime.h>
#include <math.h>

// Sizes fixed by the reference.
#define BSZ  16
#define DIM  1024
#define DPB  16        // d-channels per tile (64B global granule)
#define THREADS 1024   // waves 0-7 compute, waves 8-15 memory
#define TPB  4         // tiles per block (b = 4*bq + k), grid = 256 = 1 block/CU
#define SSTRIDE 17     // LDS float-stride per s-cell: 17*31=527==15 (mod 32)
#define BUFF 17472     // floats per buffer (covers prefetch overrun)
#define LDSB (2 * BUFF * 4)   // 139776 B -> 1 block/CU

__device__ __forceinline__ float sigmoidf_(float v) {
    return __builtin_amdgcn_rcpf(1.0f + __expf(-v));
}

// Barrier WITHOUT the vmcnt(0) drain __syncthreads() emits. Only LDS
// visibility (lgkmcnt) is required across phases: compute and memory waves
// touch disjoint LDS buffers within a phase, and global stores/loads are
// allowed to stay in flight across the barrier (stores retire in background;
// prefetch-load consumption is ordered by the compiler's counted vmcnt wait
// at the first use of L). This is the m201/HK counted-vmcnt pattern.
__device__ __forceinline__ void soft_barrier() {
    asm volatile("s_waitcnt lgkmcnt(0)" ::: "memory");
    __builtin_amdgcn_s_barrier();
    asm volatile("" ::: "memory");
}

extern __shared__ float xs[];

// 2D SSM run as the recurrence directly on x (== causal conv with the impulse
// response == reference FFT path, by linearity/shift-invariance/causality):
//   v[i,j] = a2*h[i-1,j] + a1*v[i-1,j] + b2*x[i,j]
//   h[i,j] = a1*h[i,j-1] + a2*v[i,j-1] + b1*x[i,j]
//   y[i,j] = <h,C1*s> + <v,C2*s>;  out = silu(y + x*omega)
//
// Anti-diagonal wavefront compute (lane = row i, step ts, j = ts-i); neighbor
// state folded into v_fmac_f32_dpp wave_shr:1 (lane0 zeroed by bound_ctrl:0,
// half-wave row-0 zeroed via a1z/a2z coefficients).
//
// R13 = R12 + soft barriers. R12's counters showed SUM-like (not max-like)
// compute/memory behavior: __syncthreads()'s implicit vmcnt(0) forced full
// retirement of 64KB drain-stores + 64KB fresh prefetch-loads inside every
// iteration while all 16 waves blocked. Soft barrier waits lgkmcnt only.
__global__ __launch_bounds__(THREADS, 1) void ssm2d_kernel(
    const float* __restrict__ x,
    const float* __restrict__ A1, const float* __restrict__ A2,
    const float* __restrict__ B1, const float* __restrict__ B2,
    const float* __restrict__ C1, const float* __restrict__ C2,
    const float* __restrict__ omega,
    float* __restrict__ out)
{
    const int bx = blockIdx.x;     // 0..255
    const int bq = bx >> 6;        // 0..3  -> tiles b = 4*bq + k
    const int d0 = (bx & 63) * DPB;
    const int t  = threadIdx.x;

    const int lane = t & 63;
    const int wv   = t >> 6;               // wave 0..15
    const int i    = lane & 31;            // compute: row owned by this lane

    // ---- compute-wave coefficients (waves 0-7 only) ----
    float a1c0, a1c1, a2c0, a2c1, b1c0, b1c1, b2c0, b2c1;
    float c1s0, c1s1, c2s0, c2s1, om;
    float a1z0, a1z1, a2z0, a2z1;
    int dd = 0;
    if (t < 512) {
        dd = 2 * wv + (lane >> 5);         // image (d-index) 0..15
        const int d = d0 + dd;
        const float2 fA1 = *reinterpret_cast<const float2*>(A1 + 2 * d);
        const float2 fA2 = *reinterpret_cast<const float2*>(A2 + 2 * d);
        const float2 fB1 = *reinterpret_cast<const float2*>(B1 + 2 * d);
        const float2 fB2 = *reinterpret_cast<const float2*>(B2 + 2 * d);
        const float2 fC1 = *reinterpret_cast<const float2*>(C1 + 2 * d);
        const float2 fC2 = *reinterpret_cast<const float2*>(C2 + 2 * d);
        om   = omega[d];
        a1c0 = sigmoidf_(fA1.x) * 0.5f;  a1c1 = sigmoidf_(fA1.y) * 0.5f;
        a2c0 = sigmoidf_(fA2.x) * 0.5f;  a2c1 = sigmoidf_(fA2.y) * 0.5f;
        b1c0 = sigmoidf_(fB1.x) * 0.5f;  b1c1 = sigmoidf_(fB1.y) * 0.5f;
        b2c0 = sigmoidf_(fB2.x) * 0.5f;  b2c1 = sigmoidf_(fB2.y) * 0.5f;
        const float sc = 0.70710678118654752f;
        c1s0 = fC1.x * sc;  c1s1 = fC1.y * sc;
        c2s0 = fC2.x * sc;  c2s1 = fC2.y * sc;
        a1z0 = (i == 0) ? 0.f : a1c0;  a1z1 = (i == 0) ? 0.f : a1c1;
        a2z0 = (i == 0) ? 0.f : a2c0;  a2z1 = (i == 0) ? 0.f : a2c1;
    }

    // ---- memory-wave mappings & the single rolling load set ----
    const int m    = t & 511;
    const int srow = m >> 2;               // 0..127
    const int qq   = (m & 3) * 4;
    const size_t gb = (size_t)srow * (BSZ * DIM) + d0 + qq;
    float4 L[8];

#define ISSUE(TILE) do {                                                     \
        const float* gp = x + gb + (size_t)(TILE) * DIM;                     \
        _Pragma("unroll") for (int k2 = 0; k2 < 8; ++k2)                     \
            L[k2] = *reinterpret_cast<const float4*>(                        \
                gp + (size_t)k2 * (128 * BSZ * DIM));                        \
    } while (0)

#define STAGEFROM(BUFO) do {                                                 \
        _Pragma("unroll") for (int k2 = 0; k2 < 8; ++k2) {                   \
            float* p = (BUFO) + SSTRIDE * (srow + 128 * k2) + qq;            \
            p[0] = L[k2].x; p[1] = L[k2].y;                                  \
            p[2] = L[k2].z; p[3] = L[k2].w; }                                \
    } while (0)

#define DRAINTO(TILE, BUFO) do {                                             \
        float* op = out + gb + (size_t)(TILE) * DIM;                         \
        _Pragma("unroll") for (int k2 = 0; k2 < 8; ++k2) {                   \
            const float* p = (BUFO) + SSTRIDE * (srow + 128 * k2) + qq;      \
            float4 v; v.x = p[0]; v.y = p[1]; v.z = p[2]; v.w = p[3];        \
            *reinterpret_cast<float4*>(                                      \
                op + (size_t)k2 * (128 * BSZ * DIM)) = v; }                  \
    } while (0)

    // ---- prologue: all threads stage tile 0; memory waves also issue L(t1) ----
    {
        const int srow4 = t >> 2;          // 0..255
        const int qq4   = (t & 3) * 4;
        const float* gp0 = x + (size_t)srow4 * (BSZ * DIM)
                             + (size_t)(4 * bq) * DIM + d0 + qq4;
        float4 P[4];
        #pragma unroll
        for (int k2 = 0; k2 < 4; ++k2)
            P[k2] = *reinterpret_cast<const float4*>(
                gp0 + (size_t)k2 * (256 * BSZ * DIM));
        if (t >= 512) ISSUE(4 * bq + 1);   // stays in flight past the barrier
        #pragma unroll
        for (int k2 = 0; k2 < 4; ++k2) {
            float* p = xs + SSTRIDE * (srow4 + 256 * k2) + qq4;
            p[0] = P[k2].x; p[1] = P[k2].y; p[2] = P[k2].z; p[3] = P[k2].w;
        }
    }
    soft_barrier();

    // ---- compute step macros ----
#define SBODY(XV_EXPR)                                                       \
        const float xv = (XV_EXPR);                                          \
        const float t10 = b1c0 * xv, t11 = b1c1 * xv;                        \
        const float hn0 = fmaf(a1c0, h0, fmaf(a2c0, v0, t10));               \
        const float hn1 = fmaf(a1c1, h1, fmaf(a2c1, v1, t11));               \
        float vn0 = b2c0 * xv, vn1 = b2c1 * xv;                              \
        asm("s_nop 1\n\t"                                                    \
            "v_fmac_f32_dpp %0, %2, %6 wave_shr:1 row_mask:0xf bank_mask:0xf bound_ctrl:0\n\t" \
            "v_fmac_f32_dpp %1, %3, %7 wave_shr:1 row_mask:0xf bank_mask:0xf bound_ctrl:0\n\t" \
            "v_fmac_f32_dpp %0, %4, %8 wave_shr:1 row_mask:0xf bank_mask:0xf bound_ctrl:0\n\t" \
            "v_fmac_f32_dpp %1, %5, %9 wave_shr:1 row_mask:0xf bank_mask:0xf bound_ctrl:0"     \
            : "+v"(vn0), "+v"(vn1)                                           \
            : "v"(h0), "v"(h1), "v"(v0), "v"(v1),                            \
              "v"(a2z0), "v"(a2z1), "v"(a1z0), "v"(a1z1));                   \
        float y = hn0 * c1s0;                                                \
        y = fmaf(hn1, c1s1, y);                                              \
        y = fmaf(vn0, c2s0, y);                                              \
        y = fmaf(vn1, c2s1, y);                                              \
        const float z = fmaf(xv, om, y);                                     \
        const float o = z * sigmoidf_(z);

#define SSTEP_PRE(TS, XQ) do {                                               \
        const bool val = (i <= (TS));                                        \
        SBODY(val ? (XQ) : 0.f)                                              \
        if (val) rp[SSTRIDE * (TS)] = o;                                     \
        h0 = hn0; h1 = hn1; v0 = vn0; v1 = vn1; } while (0)

#define SSTEP_POST(TS, XQ) do { SBODY(XQ)                                    \
        if (i >= (TS) - 31) rp[SSTRIDE * (TS)] = o;                          \
        h0 = hn0; h1 = hn1; v0 = vn0; v1 = vn1; } while (0)

    // ---- main loop: one soft barrier per tile ----
    #pragma unroll 1
    for (int k = 0; k < TPB; ++k) {
        if (t < 512) {
            // -------- compute waves --------
            float* rp = xs + (k & 1) * BUFF + 527 * i + dd;
            float h0 = 0.f, h1 = 0.f, v0 = 0.f, v1 = 0.f;
            float xq0 = rp[0 * SSTRIDE];
            float xq1 = rp[1 * SSTRIDE];
            float xq2 = rp[2 * SSTRIDE];
            #pragma unroll
            for (int ts = 0; ts < 30; ts += 3) {
                SSTEP_PRE(ts + 0, xq0); xq0 = rp[SSTRIDE * (ts + 3)];
                SSTEP_PRE(ts + 1, xq1); xq1 = rp[SSTRIDE * (ts + 4)];
                SSTEP_PRE(ts + 2, xq2); xq2 = rp[SSTRIDE * (ts + 5)];
            }
            SSTEP_PRE(30, xq0); xq0 = rp[SSTRIDE * 33];
            #pragma unroll
            for (int ts = 31; ts < 61; ts += 3) {
                SSTEP_POST(ts + 0, xq1); xq1 = rp[SSTRIDE * (ts + 3)];
                SSTEP_POST(ts + 1, xq2); xq2 = rp[SSTRIDE * (ts + 4)];
                SSTEP_POST(ts + 2, xq0); xq0 = rp[SSTRIDE * (ts + 5)];
            }
            SSTEP_POST(61, xq1);
            SSTEP_POST(62, xq2);
        } else {
            // -------- memory waves (rolling single load set) --------
            float* bufO = xs + ((k + 1) & 1) * BUFF;
            if (k >= 1) DRAINTO(4 * bq + k - 1, bufO);  // read bufO first
            if (k <= 2) STAGEFROM(bufO);                // L from iter k-1: ready
            if (k <= 1) ISSUE(4 * bq + k + 2);          // refill L for iter k+1
        }
        soft_barrier();
    }

    // ---- epilogue: all 1024 threads drain tile 3 from buf1 ----
    {
        const int srow4 = t >> 2;
        const int qq4   = (t & 3) * 4;
        const float* bufE = xs + ((TPB - 1) & 1) * BUFF;
        float* op = out + (size_t)srow4 * (BSZ * DIM)
                        + (size_t)(4 * bq + TPB - 1) * DIM + d0 + qq4;
        #pragma unroll
        for (int k2 = 0; k2 < 4; ++k2) {
            const float* p = bufE + SSTRIDE * (srow4 + 256 * k2) + qq4;
            float4 v; v.x = p[0]; v.y = p[1]; v.z = p[2]; v.w = p[3];
            *reinterpret_cast<float4*>(op + (size_t)k2 * (256 * BSZ * DIM)) = v;
        }
    }
}

extern "C" void kernel_launch(void* const* d_in, const int* in_sizes, int n_in,
                              void* d_out, int out_size, void* d_ws, size_t ws_size,
                              hipStream_t stream) {
    const float* x     = (const float*)d_in[0];
    const float* A1    = (const float*)d_in[1];
    const float* A2    = (const float*)d_in[2];
    const float* B1    = (const float*)d_in[3];
    const float* B2    = (const float*)d_in[4];
    const float* C1    = (const float*)d_in[5];
    const float* C2    = (const float*)d_in[6];
    const float* omega = (const float*)d_in[7];
    float* out = (float*)d_out;

    (void)hipFuncSetAttribute(reinterpret_cast<const void*>(ssm2d_kernel),
                              hipFuncAttributeMaxDynamicSharedMemorySize, LDSB);

    dim3 grid(256);                 // 64 d-groups x 4 b-quads; 4 tiles/block
    dim3 block(THREADS);
    hipLaunchKernelGGL(ssm2d_kernel, grid, block, LDSB, stream,
                       x, A1, A2, B1, B2, C1, C2, omega, out);
}

// Round 14
// 38.490 us; speedup vs baseline: 1.1795x; 1.1634x over previous
//
#include <hip/hip_runtime.h>
#include <math.h>

// Sizes fixed by the reference.
#define BSZ  16
#define DIM  1024
#define DPB  16        // d-channels per tile
#define THREADS 1024   // waves 0-7 compute, waves 8-15 memory
#define TPB  4         // tiles per block (b = 4*bq + k), grid = 256 = 1 block/CU
#define SSTRIDE 17     // LDS float-stride per s-cell: 17*31=527==15 (mod 32)
#define BUFF 17472     // floats per buffer (covers prefetch overrun)
#define LDSB (2 * BUFF * 4)   // 139776 B -> 1 block/CU

__device__ __forceinline__ float sigmoidf_(float v) {
    return __builtin_amdgcn_rcpf(1.0f + __expf(-v));
}

// Barrier without __syncthreads()'s implicit vmcnt(0) drain: only LDS
// visibility is needed across phases (global stores retire in background,
// prefetch-load consumption is ordered by the compiler's counted vmcnt).
__device__ __forceinline__ void soft_barrier() {
    asm volatile("s_waitcnt lgkmcnt(0)" ::: "memory");
    __builtin_amdgcn_s_barrier();
    asm volatile("" ::: "memory");
}

extern __shared__ float xs[];

// 2D SSM run as the recurrence directly on x (== causal conv with the impulse
// response == reference FFT path, by linearity/shift-invariance/causality).
//
// R14 = R7 structure (proven 40.6us: ISSUE(k+1) -> DRAIN(k-1) -> STAGE(k+1),
// same-phase consume) + soft barriers + PRE/POST single-mask steps + the key
// change: XCD-CONTIGUITY SWIZZLE. Every schedule R5-R13 plateaued at
// hbm ~3.0-3.3 TB/s (131MB/3TB/s = 44us = measured) because each block
// touches only 64B per (s,b) row (d-span 16 floats), scattered 64KB apart.
// Swizzle block index so XCD x (default assignment = blockIdx%8) hosts
// d-groups [8x, 8x+8): the XCD's 32 CUs collectively cover 512B-contiguous
// d-spans per (s,b) row in a tight time window -> DRAM row/channel locality.
__global__ __launch_bounds__(THREADS, 1) void ssm2d_kernel(
    const float* __restrict__ x,
    const float* __restrict__ A1, const float* __restrict__ A2,
    const float* __restrict__ B1, const float* __restrict__ B2,
    const float* __restrict__ C1, const float* __restrict__ C2,
    const float* __restrict__ omega,
    float* __restrict__ out)
{
    // ---- XCD-contiguity swizzle: XCD = lx&7 hosts dgrps 8*(lx&7)+hi ----
    const int lx   = blockIdx.x;           // 0..255
    const int xcd  = lx & 7;
    const int hi   = (lx >> 3) & 7;
    const int bq   = lx >> 6;              // 0..3 -> tiles b = 4*bq + k
    const int dgrp = 8 * xcd + hi;         // 0..63
    const int d0   = dgrp * DPB;
    const int t    = threadIdx.x;

    const int lane = t & 63;
    const int wv   = t >> 6;               // wave 0..15
    const int i    = lane & 31;            // compute: row owned by this lane

    // ---- compute-wave coefficients (waves 0-7 only) ----
    float a1c0, a1c1, a2c0, a2c1, b1c0, b1c1, b2c0, b2c1;
    float c1s0, c1s1, c2s0, c2s1, om;
    float a1z0, a1z1, a2z0, a2z1;
    int dd = 0;
    if (t < 512) {
        dd = 2 * wv + (lane >> 5);         // image (d-index) 0..15
        const int d = d0 + dd;
        const float2 fA1 = *reinterpret_cast<const float2*>(A1 + 2 * d);
        const float2 fA2 = *reinterpret_cast<const float2*>(A2 + 2 * d);
        const float2 fB1 = *reinterpret_cast<const float2*>(B1 + 2 * d);
        const float2 fB2 = *reinterpret_cast<const float2*>(B2 + 2 * d);
        const float2 fC1 = *reinterpret_cast<const float2*>(C1 + 2 * d);
        const float2 fC2 = *reinterpret_cast<const float2*>(C2 + 2 * d);
        om   = omega[d];
        a1c0 = sigmoidf_(fA1.x) * 0.5f;  a1c1 = sigmoidf_(fA1.y) * 0.5f;
        a2c0 = sigmoidf_(fA2.x) * 0.5f;  a2c1 = sigmoidf_(fA2.y) * 0.5f;
        b1c0 = sigmoidf_(fB1.x) * 0.5f;  b1c1 = sigmoidf_(fB1.y) * 0.5f;
        b2c0 = sigmoidf_(fB2.x) * 0.5f;  b2c1 = sigmoidf_(fB2.y) * 0.5f;
        const float sc = 0.70710678118654752f;
        c1s0 = fC1.x * sc;  c1s1 = fC1.y * sc;
        c2s0 = fC2.x * sc;  c2s1 = fC2.y * sc;
        a1z0 = (i == 0) ? 0.f : a1c0;  a1z1 = (i == 0) ? 0.f : a1c1;
        a2z0 = (i == 0) ? 0.f : a2c0;  a2z1 = (i == 0) ? 0.f : a2c1;
    }

    // ---- memory-wave mappings & load set ----
    const int m    = t & 511;
    const int srow = m >> 2;               // 0..127
    const int qq   = (m & 3) * 4;
    const size_t gb = (size_t)srow * (BSZ * DIM) + d0 + qq;
    float4 L[8];

#define ISSUE(TILE) do {                                                     \
        const float* gp = x + gb + (size_t)(TILE) * DIM;                     \
        _Pragma("unroll") for (int k2 = 0; k2 < 8; ++k2)                     \
            L[k2] = *reinterpret_cast<const float4*>(                        \
                gp + (size_t)k2 * (128 * BSZ * DIM));                        \
    } while (0)

#define STAGEFROM(BUFO) do {                                                 \
        _Pragma("unroll") for (int k2 = 0; k2 < 8; ++k2) {                   \
            float* p = (BUFO) + SSTRIDE * (srow + 128 * k2) + qq;            \
            p[0] = L[k2].x; p[1] = L[k2].y;                                  \
            p[2] = L[k2].z; p[3] = L[k2].w; }                                \
    } while (0)

#define DRAINTO(TILE, BUFO) do {                                             \
        float* op = out + gb + (size_t)(TILE) * DIM;                         \
        _Pragma("unroll") for (int k2 = 0; k2 < 8; ++k2) {                   \
            const float* p = (BUFO) + SSTRIDE * (srow + 128 * k2) + qq;      \
            float4 v; v.x = p[0]; v.y = p[1]; v.z = p[2]; v.w = p[3];        \
            *reinterpret_cast<float4*>(                                      \
                op + (size_t)k2 * (128 * BSZ * DIM)) = v; }                  \
    } while (0)

    // ---- prologue: all 1024 threads stage tile 0 into buf0 ----
    {
        const int srow4 = t >> 2;          // 0..255
        const int qq4   = (t & 3) * 4;
        const float* gp0 = x + (size_t)srow4 * (BSZ * DIM)
                             + (size_t)(4 * bq) * DIM + d0 + qq4;
        float4 P[4];
        #pragma unroll
        for (int k2 = 0; k2 < 4; ++k2)
            P[k2] = *reinterpret_cast<const float4*>(
                gp0 + (size_t)k2 * (256 * BSZ * DIM));
        #pragma unroll
        for (int k2 = 0; k2 < 4; ++k2) {
            float* p = xs + SSTRIDE * (srow4 + 256 * k2) + qq4;
            p[0] = P[k2].x; p[1] = P[k2].y; p[2] = P[k2].z; p[3] = P[k2].w;
        }
    }
    soft_barrier();

    // ---- compute step macros ----
#define SBODY(XV_EXPR)                                                       \
        const float xv = (XV_EXPR);                                          \
        const float t10 = b1c0 * xv, t11 = b1c1 * xv;                        \
        const float hn0 = fmaf(a1c0, h0, fmaf(a2c0, v0, t10));               \
        const float hn1 = fmaf(a1c1, h1, fmaf(a2c1, v1, t11));               \
        float vn0 = b2c0 * xv, vn1 = b2c1 * xv;                              \
        asm("s_nop 1\n\t"                                                    \
            "v_fmac_f32_dpp %0, %2, %6 wave_shr:1 row_mask:0xf bank_mask:0xf bound_ctrl:0\n\t" \
            "v_fmac_f32_dpp %1, %3, %7 wave_shr:1 row_mask:0xf bank_mask:0xf bound_ctrl:0\n\t" \
            "v_fmac_f32_dpp %0, %4, %8 wave_shr:1 row_mask:0xf bank_mask:0xf bound_ctrl:0\n\t" \
            "v_fmac_f32_dpp %1, %5, %9 wave_shr:1 row_mask:0xf bank_mask:0xf bound_ctrl:0"     \
            : "+v"(vn0), "+v"(vn1)                                           \
            : "v"(h0), "v"(h1), "v"(v0), "v"(v1),                            \
              "v"(a2z0), "v"(a2z1), "v"(a1z0), "v"(a1z1));                   \
        float y = hn0 * c1s0;                                                \
        y = fmaf(hn1, c1s1, y);                                              \
        y = fmaf(vn0, c2s0, y);                                              \
        y = fmaf(vn1, c2s1, y);                                              \
        const float z = fmaf(xv, om, y);                                     \
        const float o = z * sigmoidf_(z);

#define SSTEP_PRE(TS, XQ) do {                                               \
        const bool val = (i <= (TS));                                        \
        SBODY(val ? (XQ) : 0.f)                                              \
        if (val) rp[SSTRIDE * (TS)] = o;                                     \
        h0 = hn0; h1 = hn1; v0 = vn0; v1 = vn1; } while (0)

#define SSTEP_POST(TS, XQ) do { SBODY(XQ)                                    \
        if (i >= (TS) - 31) rp[SSTRIDE * (TS)] = o;                          \
        h0 = hn0; h1 = hn1; v0 = vn0; v1 = vn1; } while (0)

    // ---- main loop: one soft barrier per tile ----
    #pragma unroll 1
    for (int k = 0; k < TPB; ++k) {
        if (t < 512) {
            // -------- compute waves --------
            float* rp = xs + (k & 1) * BUFF + 527 * i + dd;
            float h0 = 0.f, h1 = 0.f, v0 = 0.f, v1 = 0.f;
            float xq0 = rp[0 * SSTRIDE];
            float xq1 = rp[1 * SSTRIDE];
            float xq2 = rp[2 * SSTRIDE];
            #pragma unroll
            for (int ts = 0; ts < 30; ts += 3) {
                SSTEP_PRE(ts + 0, xq0); xq0 = rp[SSTRIDE * (ts + 3)];
                SSTEP_PRE(ts + 1, xq1); xq1 = rp[SSTRIDE * (ts + 4)];
                SSTEP_PRE(ts + 2, xq2); xq2 = rp[SSTRIDE * (ts + 5)];
            }
            SSTEP_PRE(30, xq0); xq0 = rp[SSTRIDE * 33];
            #pragma unroll
            for (int ts = 31; ts < 61; ts += 3) {
                SSTEP_POST(ts + 0, xq1); xq1 = rp[SSTRIDE * (ts + 3)];
                SSTEP_POST(ts + 1, xq2); xq2 = rp[SSTRIDE * (ts + 4)];
                SSTEP_POST(ts + 2, xq0); xq0 = rp[SSTRIDE * (ts + 5)];
            }
            SSTEP_POST(61, xq1);
            SSTEP_POST(62, xq2);
        } else {
            // -------- memory waves (R7 order: issue, drain, stage) --------
            float* bufO = xs + ((k + 1) & 1) * BUFF;
            if (k < TPB - 1) ISSUE(4 * bq + k + 1);      // head start
            if (k >= 1) DRAINTO(4 * bq + k - 1, bufO);   // read bufO first
            if (k < TPB - 1) STAGEFROM(bufO);            // consume same-phase L
        }
        soft_barrier();
    }

    // ---- epilogue: all 1024 threads drain tile 3 from buf1 ----
    {
        const int srow4 = t >> 2;
        const int qq4   = (t & 3) * 4;
        const float* bufE = xs + ((TPB - 1) & 1) * BUFF;
        float* op = out + (size_t)srow4 * (BSZ * DIM)
                        + (size_t)(4 * bq + TPB - 1) * DIM + d0 + qq4;
        #pragma unroll
        for (int k2 = 0; k2 < 4; ++k2) {
            const float* p = bufE + SSTRIDE * (srow4 + 256 * k2) + qq4;
            float4 v; v.x = p[0]; v.y = p[1]; v.z = p[2]; v.w = p[3];
            *reinterpret_cast<float4*>(op + (size_t)k2 * (256 * BSZ * DIM)) = v;
        }
    }
}

extern "C" void kernel_launch(void* const* d_in, const int* in_sizes, int n_in,
                              void* d_out, int out_size, void* d_ws, size_t ws_size,
                              hipStream_t stream) {
    const float* x     = (const float*)d_in[0];
    const float* A1    = (const float*)d_in[1];
    const float* A2    = (const float*)d_in[2];
    const float* B1    = (const float*)d_in[3];
    const float* B2    = (const float*)d_in[4];
    const float* C1    = (const float*)d_in[5];
    const float* C2    = (const float*)d_in[6];
    const float* omega = (const float*)d_in[7];
    float* out = (float*)d_out;

    (void)hipFuncSetAttribute(reinterpret_cast<const void*>(ssm2d_kernel),
                              hipFuncAttributeMaxDynamicSharedMemorySize, LDSB);

    dim3 grid(256);                 // 64 d-groups x 4 b-quads; 4 tiles/block
    dim3 block(THREADS);
    hipLaunchKernelGGL(ssm2d_kernel, grid, block, LDSB, stream,
                       x, A1, A2, B1, B2, C1, C2, omega, out);
}